// Round 11
// baseline (683.841 us; speedup 1.0000x reference)
//
#include <hip/hip_runtime.h>
#include <stdint.h>

#define NN 50000
#define DEG 16
#define MT 16
#define NBLK (NN / MT)                 // 3125 exact
#define MTG 64
#define NBLKG ((NN + MTG - 1) / MTG)   // 782
#define LOG2E 1.4426950408889634f
#define GXR 520                        // GXS row stride in u16 (1040 B, bank-spread)

typedef short bf16x8 __attribute__((ext_vector_type(8)));
typedef float f32x4 __attribute__((ext_vector_type(4)));
typedef unsigned short u16;
typedef unsigned int u32;

static __device__ __forceinline__ u16 f2bf(float f) {
  union { float f; u32 u; } v; v.f = f;
  u32 u = v.u + 0x7FFFu + ((v.u >> 16) & 1u);   // round-to-nearest-even
  return (u16)(u >> 16);
}
static __device__ __forceinline__ float rcp_(float x) {
  return __builtin_amdgcn_rcpf(x);
}
static __device__ __forceinline__ float ex2_(float x) {
  return __builtin_amdgcn_exp2f(x);
}
static __device__ __forceinline__ float bfhi2f(u32 hibits) {
  union { u32 u; float f; } v; v.u = hibits; return v.f;
}
static __device__ __forceinline__ void gload_lds16(const void* g, void* l) {
  __builtin_amdgcn_global_load_lds(
      (const __attribute__((address_space(1))) void*)g,
      (__attribute__((address_space(3))) void*)l, 16, 0, 0);
}

// ---------------------------------------------------------------------------
// Prep (v7/v10 layout): bf16-convert x, prepack MFMA B-fragments, bias sums.
// Gate weights/biases PRE-SCALED by log2e (i,f,o) / 2*log2e (g).
//   wpk[(((w*4+g)*8+kt)*64+lane)*8+j] = sc * W[col][k],
//   col = g*128 + w*16 + (lane&15),  k = kt*32 + (lane>>4)*8 + j,
//   W = [w_ih | w_hh] along K  (kt 0..3 = x-part, kt 4..7 = h-part).
// ---------------------------------------------------------------------------
__global__ void k_prep(const float* __restrict__ x, u16* __restrict__ xb,
                       const float* __restrict__ wih1, const float* __restrict__ whh1, u16* __restrict__ wpk1,
                       const float* __restrict__ wih2, const float* __restrict__ whh2, u16* __restrict__ wpk2,
                       const float* __restrict__ lr1, const float* __restrict__ ll1, u16* __restrict__ epk1,
                       const float* __restrict__ lr2, const float* __restrict__ ll2, u16* __restrict__ epk2,
                       const float* __restrict__ linw, u16* __restrict__ hpk,
                       const float* __restrict__ bi1, const float* __restrict__ bh1, float* __restrict__ bs1,
                       const float* __restrict__ bi2, const float* __restrict__ bh2, float* __restrict__ bs2) {
  int b = blockIdx.x;
  if (b < 128) {
    const float* wih = (b < 64) ? wih1 : wih2;
    const float* whh = (b < 64) ? whh1 : whh2;
    u16* wpk = (b < 64) ? wpk1 : wpk2;
    int t = (b & 63) * 256 + threadIdx.x;          // 0..16383
    int lane = t & 63, kt = (t >> 6) & 7, g = (t >> 9) & 3, w = (t >> 11) & 7;
    int col = g * 128 + w * 16 + (lane & 15);
    int k0 = kt * 32 + (lane >> 4) * 8;
    float sc = (g == 2) ? 2.f * LOG2E : LOG2E;
#pragma unroll
    for (int j = 0; j < 8; ++j) {
      int k = k0 + j;
      float v = (k < 128) ? wih[col * 128 + k] : whh[col * 128 + k - 128];
      wpk[t * 8 + j] = f2bf(sc * v);
    }
  } else if (b < 160) {
    const float* lrw = (b < 144) ? lr1 : lr2;
    const float* llw = (b < 144) ? ll1 : ll2;
    u16* epk = (b < 144) ? epk1 : epk2;
    int t = ((b - 128) & 15) * 256 + threadIdx.x;  // 0..4095
    int lane = t & 63, kt = (t >> 6) & 7, w = (t >> 9) & 7;
    int col = w * 16 + (lane & 15);
    int k0 = kt * 32 + (lane >> 4) * 8;
#pragma unroll
    for (int j = 0; j < 8; ++j) {
      int k = k0 + j;
      epk[t * 8 + j] = f2bf(k < 128 ? lrw[col * 128 + k] : llw[col * 128 + k - 128]);
    }
  } else if (b < 164) {
    int t = (b - 160) * 256 + threadIdx.x;         // 0..1023
    int lane = t & 63, kt = (t >> 6) & 3, w = (t >> 8) & 3;
    int col = w * 16 + (lane & 15);
    int k0 = kt * 32 + (lane >> 4) * 8;
#pragma unroll
    for (int j = 0; j < 8; ++j) hpk[t * 8 + j] = f2bf(linw[col * 128 + k0 + j]);
  } else if (b < 168) {
    int t = (b - 164) * 256 + threadIdx.x;         // 0..1023
    if (t < 1024) {
      int i = t & 511;
      float sc = ((i >> 7) == 2) ? 2.f * LOG2E : LOG2E;
      if (t < 512) bs1[i] = sc * (bi1[i] + bh1[i]);
      else bs2[i] = sc * (bi2[i] + bh2[i]);
    }
  } else {
    int i = (b - 168) * 256 + threadIdx.x;
    int stride = (gridDim.x - 168) * 256;
    for (; i < NN * 128 / 4; i += stride) {
      float4 v = ((const float4*)x)[i];
      ushort4 o;
      o.x = f2bf(v.x); o.y = f2bf(v.y); o.z = f2bf(v.z); o.w = f2bf(v.w);
      ((ushort4*)xb)[i] = o;
    }
  }
}

// ---------------------------------------------------------------------------
// GX precompute: GX[n, col'] = x[n] @ W_ih^T + bias (pre-scaled domain).
// Dense GEMM M=50000, N=512, K=128 — removes the ~16x redundant per-edge
// x-projection from the layer kernel (105 GFLOP -> 6.5 GFLOP).
// Output col-permuted for the layer's b64 gate reads:
//   GX[n][w*64 + lr*4 + g]  (bf16; per (n,w,lr): 4 gates packed in 8 bytes)
// ---------------------------------------------------------------------------
__global__ __launch_bounds__(512, 2) void k_gx(
    const u16* __restrict__ xin, const u16* __restrict__ wpk,
    const float* __restrict__ bsum, u16* __restrict__ gx) {
  const int tid = threadIdx.x;
  const int w = tid >> 6, l = tid & 63;
  const int lr = l & 15, lh = l >> 4;
  const int node0 = blockIdx.x * MTG;

  bf16x8 wreg[4][4];
#pragma unroll
  for (int g = 0; g < 4; ++g)
#pragma unroll
    for (int kt = 0; kt < 4; ++kt)
      wreg[g][kt] = *(const bf16x8*)(wpk + (size_t)(((w * 4 + g) * 8 + kt) * 64 + l) * 8);

  float gb[4];
#pragma unroll
  for (int g = 0; g < 4; ++g) gb[g] = bsum[g * 128 + w * 16 + lr];

#pragma unroll
  for (int mt = 0; mt < 4; ++mt) {
    int anode = node0 + mt * 16 + lr;
    if (anode >= NN) anode = NN - 1;
    const u16* b_ = xin + (size_t)anode * 128 + lh * 8;
    bf16x8 xf[4];
#pragma unroll
    for (int kt = 0; kt < 4; ++kt) xf[kt] = *(const bf16x8*)(b_ + kt * 32);
    f32x4 acc[4];
#pragma unroll
    for (int g = 0; g < 4; ++g) acc[g] = (f32x4){gb[g], gb[g], gb[g], gb[g]};
#pragma unroll
    for (int kt = 0; kt < 4; ++kt)
#pragma unroll
      for (int g = 0; g < 4; ++g)
        acc[g] = __builtin_amdgcn_mfma_f32_16x16x32_bf16(xf[kt], wreg[g][kt], acc[g], 0, 0, 0);
#pragma unroll
    for (int r = 0; r < 4; ++r) {
      int nd = node0 + mt * 16 + lh * 4 + r;
      if (nd < NN) {
        u32 lo = (u32)f2bf(acc[0][r]) | ((u32)f2bf(acc[1][r]) << 16);
        u32 hi = (u32)f2bf(acc[2][r]) | ((u32)f2bf(acc[3][r]) << 16);
        *(uint2*)((char*)gx + (size_t)nd * 1024 + w * 128 + lr * 8) =
            make_uint2(lo, hi);
      }
    }
  }
}

// ---------------------------------------------------------------------------
// Fused SAGE-LSTM layer, v11 (GX path): 512 thr = 8 waves, MT=16, 2 blocks/CU.
//  * x-part MFMAs GONE: per step, gather precomputed gate rows GX[idx] (1KB,
//    incl. bias) into triple-buffered LDS via global_load_lds; EW reads all 4
//    gates per element as ONE ds_read_b64 (GX col-permuted; 1040B row stride
//    -> 2-way banks = free).
//  * wreg = h-panel only (16 frags, 64 VGPR) -> ~115 regs ->
//    __launch_bounds__(512,4): 4 waves/SIMD across 2 INDEPENDENT blocks
//    (2 barrier domains/SIMD — the chain overlap v9's single block lacked).
//  * counted CBAR(2): batch s+2 stays in flight across the barrier.
// AH swizzle: byte ^= (row&15)<<4 (v10 verbatim). EW math identical to v10.
// ---------------------------------------------------------------------------

#define STAGE(S, B)                                                           \
  do {                                                                        \
    _Pragma("unroll") for (int p = 0; p < 2; ++p) {                           \
      int row_ = 2 * w + p;                                                   \
      int idx_ = IDXT[(S) * 16 + row_];                                       \
      gload_lds16((const char*)gxg + (size_t)idx_ * 1024 + l * 16,            \
                  GXS[B] + row_ * GXR);                                       \
    }                                                                         \
  } while (0)

#define CBAR(N)                                                               \
  do {                                                                        \
    asm volatile("s_waitcnt vmcnt(" #N ") lgkmcnt(0)" ::: "memory");          \
    __builtin_amdgcn_s_barrier();                                             \
    __builtin_amdgcn_sched_barrier(0);                                        \
  } while (0)

template <int L2>
__global__ __launch_bounds__(512, 4) void k_layer_gx(
    const u16* __restrict__ xin, const int* __restrict__ src,
    const u16* __restrict__ wpk, const u16* __restrict__ gxg,
    const u16* __restrict__ epk, const float* __restrict__ linlb,
    u16* __restrict__ hout, const u16* __restrict__ hpk,
    const float* __restrict__ linb, float* __restrict__ dout) {
  __shared__ __align__(16) u16 GXS[3][MT * GXR];  // 3 x 16,640 B
  __shared__ __align__(16) u16 AH[2][MT * 128];   // 2 x 4 KB
  __shared__ int IDXT[DEG * MT];                  // transposed [d][r], 1 KB

  const int tid = threadIdx.x;
  const int w = tid >> 6, l = tid & 63;
  const int lr = l & 15, lh = l >> 4;
  const int node0 = blockIdx.x * MT;

  // h-part weight panel only: 16 frags = 64 VGPRs (wpk kt 4..7)
  bf16x8 wreg[4][4];
#pragma unroll
  for (int g = 0; g < 4; ++g)
#pragma unroll
    for (int kt = 0; kt < 4; ++kt)
      wreg[g][kt] = *(const bf16x8*)(wpk + (size_t)(((w * 4 + g) * 8 + 4 + kt) * 64 + l) * 8);

  if (tid < MT * DEG)
    IDXT[(tid & 15) * 16 + (tid >> 4)] = src[node0 * DEG + tid];

  float eb = linlb[w * 16 + lr];
  __syncthreads();  // IDXT ready

  // prologue: stage gx(0) -> GXS[0], gx(1) -> GXS[1]
  STAGE(0, 0);
  STAGE(1, 1);

  f32x4 acc[4];
#pragma unroll
  for (int g = 0; g < 4; ++g) acc[g] = (f32x4){0.f, 0.f, 0.f, 0.f};
  f32x4 c4 = (f32x4){0.f, 0.f, 0.f, 0.f};
  bf16x8 xf[4];

  CBAR(2);  // gx(0) landed; gx(1) in flight

#pragma unroll 1
  for (int step = 0; step < DEG; ++step) {
    const int cb = step & 1, nb = cb ^ 1;
    const int sb = step % 3;

    if (step < DEG - 2) {
      const int b2 = (step + 2) % 3;
      STAGE(step + 2, b2);
    }
    if (step == DEG - 1) {
      // own-x fragments for the epilogue (latency hidden under this step)
      const u16* b_ = xin + (size_t)(node0 + lr) * 128 + lh * 8;
#pragma unroll
      for (int kt = 0; kt < 4; ++kt) xf[kt] = *(const bf16x8*)(b_ + kt * 32);
    }

    // h-part: K tiles 4..7 from AH[cb] (h == 0 at step 0)
    if (step) {
      __builtin_amdgcn_s_setprio(1);
#pragma unroll
      for (int kt = 0; kt < 4; ++kt) {
        bf16x8 af = *(const bf16x8*)((const char*)AH[cb] + lr * 256 +
                                     ((kt * 64 + lh * 16) ^ ((lr & 15) << 4)));
#pragma unroll
        for (int g = 0; g < 4; ++g)
          acc[g] = __builtin_amdgcn_mfma_f32_16x16x32_bf16(af, wreg[g][kt], acc[g], 0, 0, 0);
      }
      __builtin_amdgcn_s_setprio(0);
    }

    // EW: gates = gx (bias + x-part, bf16) + h-part (f32 acc)
#pragma unroll
    for (int r = 0; r < 4; ++r) {
      int row = lh * 4 + r;
      uint2 gv = *(const uint2*)((const char*)GXS[sb] + row * (GXR * 2) +
                                 w * 128 + lr * 8);
      float ai = acc[0][r] + bfhi2f(gv.x << 16);
      float afv = acc[1][r] + bfhi2f(gv.x & 0xFFFF0000u);
      float ag = acc[2][r] + bfhi2f(gv.y << 16);
      float ao = acc[3][r] + bfhi2f(gv.y & 0xFFFF0000u);
      float iv = rcp_(1.f + ex2_(-ai));
      float fv = rcp_(1.f + ex2_(-afv));
      float gvv = 1.f - 2.f * rcp_(1.f + ex2_(ag));
      float ov = rcp_(1.f + ex2_(-ao));
      float cv = fv * c4[r] + iv * gvv;
      c4[r] = cv;
      float th = 1.f - 2.f * rcp_(1.f + ex2_(2.f * LOG2E * cv));
      int jj = 2 * (w * 16 + lr);
      *(u16*)((char*)AH[nb] + row * 256 + (jj ^ ((row & 15) << 4))) =
          f2bf(ov * th);
    }
    // reset h-part accumulator for the next step
#pragma unroll
    for (int g = 0; g < 4; ++g) acc[g] = (f32x4){0.f, 0.f, 0.f, 0.f};

    if (step < DEG - 2) CBAR(2);
    else CBAR(0);
  }

  // Epilogue: out = lin_r(x_own) + lin_l(h_final) + b, ReLU.
  f32x4 eacc = (f32x4){eb, eb, eb, eb};
#pragma unroll
  for (int kt = 0; kt < 4; ++kt) {
    bf16x8 bf = *(const bf16x8*)(epk + (size_t)((w * 8 + kt) * 64 + l) * 8);
    eacc = __builtin_amdgcn_mfma_f32_16x16x32_bf16(xf[kt], bf, eacc, 0, 0, 0);
  }
#pragma unroll
  for (int kt = 0; kt < 4; ++kt) {
    bf16x8 af = *(const bf16x8*)((const char*)AH[0] + lr * 256 +
                                 ((kt * 64 + lh * 16) ^ ((lr & 15) << 4)));
    bf16x8 bf = *(const bf16x8*)(epk + (size_t)((w * 8 + 4 + kt) * 64 + l) * 8);
    eacc = __builtin_amdgcn_mfma_f32_16x16x32_bf16(af, bf, eacc, 0, 0, 0);
  }

  if constexpr (!L2) {
#pragma unroll
    for (int r = 0; r < 4; ++r) {
      int node = node0 + lh * 4 + r;
      float v = fmaxf(eacc[r], 0.f);
      hout[(size_t)node * 128 + w * 16 + lr] = f2bf(v);
    }
  } else {
#pragma unroll
    for (int r = 0; r < 4; ++r) {
      int row = lh * 4 + r;
      float v = fmaxf(eacc[r], 0.f);
      int jj = 2 * (w * 16 + lr);
      *(u16*)((char*)AH[1] + row * 256 + (jj ^ ((row & 15) << 4))) = f2bf(v);
    }
    __syncthreads();
    if (w < 4) {
      float hb = linb[w * 16 + lr];
      f32x4 hacc = (f32x4){hb, hb, hb, hb};
#pragma unroll
      for (int kt = 0; kt < 4; ++kt) {
        bf16x8 af = *(const bf16x8*)((const char*)AH[1] + lr * 256 +
                                     ((kt * 64 + lh * 16) ^ ((lr & 15) << 4)));
        bf16x8 bf = *(const bf16x8*)(hpk + (size_t)((w * 4 + kt) * 64 + l) * 8);
        hacc = __builtin_amdgcn_mfma_f32_16x16x32_bf16(af, bf, hacc, 0, 0, 0);
      }
#pragma unroll
      for (int r = 0; r < 4; ++r) {
        int node = node0 + lh * 4 + r;
        dout[(size_t)node * 64 + w * 16 + lr] = hacc[r];
      }
    }
  }
}

// ---------------------------------------------------------------------------
// Fallback layer (v10 verbatim) — used only if ws_size can't hold GX.
// ---------------------------------------------------------------------------
#define FBXLOAD(DCODE)                                                        \
  do {                                                                        \
    int idx_ = ((DCODE) < DEG) ? IDXT[(DCODE) * 16 + lr] : node0 + lr;        \
    const u16* b_ = xin + (size_t)idx_ * 128 + lh * 8;                        \
    xf[0] = *(const bf16x8*)(b_);                                             \
    xf[1] = *(const bf16x8*)(b_ + 32);                                        \
    xf[2] = *(const bf16x8*)(b_ + 64);                                        \
    xf[3] = *(const bf16x8*)(b_ + 96);                                        \
  } while (0)

#define FBXPART()                                                             \
  do {                                                                        \
    __builtin_amdgcn_s_setprio(1);                                            \
    _Pragma("unroll") for (int g = 0; g < 4; ++g)                             \
        acc[g] = (f32x4){gb[g], gb[g], gb[g], gb[g]};                         \
    _Pragma("unroll") for (int kt = 0; kt < 4; ++kt)                          \
        _Pragma("unroll") for (int g = 0; g < 4; ++g)                         \
            acc[g] = __builtin_amdgcn_mfma_f32_16x16x32_bf16(xf[kt], wreg[g][kt], acc[g], 0, 0, 0); \
    __builtin_amdgcn_s_setprio(0);                                            \
  } while (0)

#define FBEBAR()                                                              \
  do {                                                                        \
    asm volatile("s_waitcnt lgkmcnt(0)" ::: "memory");                        \
    __builtin_amdgcn_s_barrier();                                             \
    __builtin_amdgcn_sched_barrier(0);                                        \
  } while (0)

template <int L2>
__global__ __launch_bounds__(512, 2) void k_layer_fb(
    const u16* __restrict__ xin, const int* __restrict__ src,
    const u16* __restrict__ wpk, const float* __restrict__ bsum,
    const u16* __restrict__ epk, const float* __restrict__ linlb,
    u16* __restrict__ hout, const u16* __restrict__ hpk,
    const float* __restrict__ linb, float* __restrict__ dout) {
  __shared__ __align__(16) u16 AH[2][MT * 128];
  __shared__ int IDXT[DEG * MT];

  const int tid = threadIdx.x;
  const int w = tid >> 6, l = tid & 63;
  const int lr = l & 15, lh = l >> 4;
  const int node0 = blockIdx.x * MT;

  bf16x8 wreg[4][8];
#pragma unroll
  for (int g = 0; g < 4; ++g)
#pragma unroll
    for (int kt = 0; kt < 8; ++kt)
      wreg[g][kt] = *(const bf16x8*)(wpk + (size_t)(((w * 4 + g) * 8 + kt) * 64 + l) * 8);

  if (tid < MT * DEG)
    IDXT[(tid & 15) * 16 + (tid >> 4)] = src[node0 * DEG + tid];

  float gb[4];
#pragma unroll
  for (int g = 0; g < 4; ++g) gb[g] = bsum[g * 128 + w * 16 + lr];
  float eb = linlb[w * 16 + lr];
  __syncthreads();

  bf16x8 xf[4];
  f32x4 acc[4];
  f32x4 c4 = (f32x4){0.f, 0.f, 0.f, 0.f};

  FBXLOAD(0);
  FBXPART();
  FBXLOAD(1);

#pragma unroll 1
  for (int step = 0; step < DEG; ++step) {
    const int cb = step & 1, nb = cb ^ 1;
    if (step) {
      __builtin_amdgcn_s_setprio(1);
#pragma unroll
      for (int kt = 0; kt < 4; ++kt) {
        bf16x8 af = *(const bf16x8*)((const char*)AH[cb] + lr * 256 +
                                     ((kt * 64 + lh * 16) ^ ((lr & 15) << 4)));
#pragma unroll
        for (int g = 0; g < 4; ++g)
          acc[g] = __builtin_amdgcn_mfma_f32_16x16x32_bf16(af, wreg[g][4 + kt], acc[g], 0, 0, 0);
      }
      __builtin_amdgcn_s_setprio(0);
    }
#pragma unroll
    for (int r = 0; r < 4; ++r) {
      float iv = rcp_(1.f + ex2_(-acc[0][r]));
      float fv = rcp_(1.f + ex2_(-acc[1][r]));
      float gv = 1.f - 2.f * rcp_(1.f + ex2_(acc[2][r]));
      float ov = rcp_(1.f + ex2_(-acc[3][r]));
      float cv = fv * c4[r] + iv * gv;
      c4[r] = cv;
      float th = 1.f - 2.f * rcp_(1.f + ex2_(2.f * LOG2E * cv));
      int row = lh * 4 + r;
      int jj = 2 * (w * 16 + lr);
      *(u16*)((char*)AH[nb] + row * 256 + (jj ^ ((row & 15) << 4))) =
          f2bf(ov * th);
    }
    if (step < DEG - 1) {
      FBXPART();
      FBXLOAD(step + 2);
    }
    FBEBAR();
  }

  f32x4 eacc = (f32x4){eb, eb, eb, eb};
#pragma unroll
  for (int kt = 0; kt < 4; ++kt) {
    bf16x8 bf = *(const bf16x8*)(epk + (size_t)((w * 8 + kt) * 64 + l) * 8);
    eacc = __builtin_amdgcn_mfma_f32_16x16x32_bf16(xf[kt], bf, eacc, 0, 0, 0);
  }
#pragma unroll
  for (int kt = 0; kt < 4; ++kt) {
    bf16x8 af = *(const bf16x8*)((const char*)AH[0] + lr * 256 +
                                 ((kt * 64 + lh * 16) ^ ((lr & 15) << 4)));
    bf16x8 bf = *(const bf16x8*)(epk + (size_t)((w * 8 + 4 + kt) * 64 + l) * 8);
    eacc = __builtin_amdgcn_mfma_f32_16x16x32_bf16(af, bf, eacc, 0, 0, 0);
  }

  if constexpr (!L2) {
#pragma unroll
    for (int r = 0; r < 4; ++r) {
      int node = node0 + lh * 4 + r;
      float v = fmaxf(eacc[r], 0.f);
      hout[(size_t)node * 128 + w * 16 + lr] = f2bf(v);
    }
  } else {
#pragma unroll
    for (int r = 0; r < 4; ++r) {
      int row = lh * 4 + r;
      float v = fmaxf(eacc[r], 0.f);
      int jj = 2 * (w * 16 + lr);
      *(u16*)((char*)AH[1] + row * 256 + (jj ^ ((row & 15) << 4))) = f2bf(v);
    }
    __syncthreads();
    if (w < 4) {
      float hb = linb[w * 16 + lr];
      f32x4 hacc = (f32x4){hb, hb, hb, hb};
#pragma unroll
      for (int kt = 0; kt < 4; ++kt) {
        bf16x8 af = *(const bf16x8*)((const char*)AH[1] + lr * 256 +
                                     ((kt * 64 + lh * 16) ^ ((lr & 15) << 4)));
        bf16x8 bf = *(const bf16x8*)(hpk + (size_t)((w * 4 + kt) * 64 + l) * 8);
        hacc = __builtin_amdgcn_mfma_f32_16x16x32_bf16(af, bf, hacc, 0, 0, 0);
      }
#pragma unroll
      for (int r = 0; r < 4; ++r) {
        int node = node0 + lh * 4 + r;
        dout[(size_t)node * 64 + w * 16 + lr] = hacc[r];
      }
    }
  }
}

extern "C" void kernel_launch(void* const* d_in, const int* in_sizes, int n_in,
                              void* d_out, int out_size, void* d_ws, size_t ws_size,
                              hipStream_t stream) {
  const float* x    = (const float*)d_in[0];
  const int*   edge = (const int*)d_in[1];   // src = first N*DEG entries
  const float* wih1 = (const float*)d_in[2];
  const float* whh1 = (const float*)d_in[3];
  const float* bih1 = (const float*)d_in[4];
  const float* bhh1 = (const float*)d_in[5];
  const float* ll1w = (const float*)d_in[6];
  const float* ll1b = (const float*)d_in[7];
  const float* lr1w = (const float*)d_in[8];
  const float* wih2 = (const float*)d_in[9];
  const float* whh2 = (const float*)d_in[10];
  const float* bih2 = (const float*)d_in[11];
  const float* bhh2 = (const float*)d_in[12];
  const float* ll2w = (const float*)d_in[13];
  const float* ll2b = (const float*)d_in[14];
  const float* lr2w = (const float*)d_in[15];
  const float* linw = (const float*)d_in[16];
  const float* linb = (const float*)d_in[17];

  char* ws = (char*)d_ws;
  u16* xb    = (u16*)(ws);                       // 12,800,000 B
  u16* h1b   = (u16*)(ws + 12800000);            // 12,800,000 B
  u16* wpk1  = (u16*)(ws + 25600000);            //    262,144 B
  u16* wpk2  = (u16*)(ws + 25862144);            //    262,144 B
  u16* epk1  = (u16*)(ws + 26124288);            //     65,536 B
  u16* epk2  = (u16*)(ws + 26189824);            //     65,536 B
  u16* hpk   = (u16*)(ws + 26255360);            //     16,384 B
  float* bs1 = (float*)(ws + 26271744);          //      2,048 B
  float* bs2 = (float*)(ws + 26273792);          //      2,048 B
  u16* gxb   = (u16*)(ws + 26280000);            // 51,200,000 B (GX)
  const size_t need = 26280000ull + 51200000ull;

  k_prep<<<1000, 256, 0, stream>>>(x, xb,
                                   wih1, whh1, wpk1, wih2, whh2, wpk2,
                                   lr1w, ll1w, epk1, lr2w, ll2w, epk2,
                                   linw, hpk,
                                   bih1, bhh1, bs1, bih2, bhh2, bs2);
  if (ws_size >= need) {
    k_gx<<<NBLKG, 512, 0, stream>>>(xb, wpk1, bs1, gxb);
    k_layer_gx<0><<<NBLK, 512, 0, stream>>>(xb, edge, wpk1, gxb, epk1, ll1b,
                                            h1b, nullptr, nullptr, nullptr);
    k_gx<<<NBLKG, 512, 0, stream>>>(h1b, wpk2, bs2, gxb);
    k_layer_gx<1><<<NBLK, 512, 0, stream>>>(h1b, edge, wpk2, gxb, epk2, ll2b,
                                            nullptr, hpk, linb, (float*)d_out);
  } else {
    k_layer_fb<0><<<NBLK, 512, 0, stream>>>(xb, edge, wpk1, bs1, epk1, ll1b,
                                            h1b, nullptr, nullptr, nullptr);
    k_layer_fb<1><<<NBLK, 512, 0, stream>>>(h1b, edge, wpk2, bs2, epk2, ll2b,
                                            nullptr, hpk, linb, (float*)d_out);
  }
}

// Round 12
// 648.668 us; speedup vs baseline: 1.0542x; 1.0542x over previous
//
#include <hip/hip_runtime.h>
#include <stdint.h>

#define NN 50000
#define DEG 16
#define MT 32
#define NBLK ((NN + MT - 1) / MT)     // 1563 (tail block: stream B partly invalid)
#define LOG2E 1.4426950408889634f

typedef short bf16x8 __attribute__((ext_vector_type(8)));
typedef float f32x4 __attribute__((ext_vector_type(4)));
typedef unsigned short u16;
typedef unsigned int u32;

static __device__ __forceinline__ u16 f2bf(float f) {
  union { float f; u32 u; } v; v.f = f;
  u32 u = v.u + 0x7FFFu + ((v.u >> 16) & 1u);   // round-to-nearest-even
  return (u16)(u >> 16);
}
static __device__ __forceinline__ float rcp_(float x) {
  return __builtin_amdgcn_rcpf(x);
}
static __device__ __forceinline__ float ex2_(float x) {
  return __builtin_amdgcn_exp2f(x);
}

// ---------------------------------------------------------------------------
// Prep (v7/v10 layout): bf16-convert x, prepack MFMA B-fragments, bias sums.
// Gate weights/biases PRE-SCALED by log2e (i,f,o) / 2*log2e (g).
//   wpk[(((w*4+g)*8+kt)*64+lane)*8+j] = sc * W[col][k],
//   col = g*128 + w*16 + (lane&15),  k = kt*32 + (lane>>4)*8 + j,
//   W = [w_ih | w_hh] along K  (kt 0..3 = x-part, kt 4..7 = h-part).
// ---------------------------------------------------------------------------
__global__ void k_prep(const float* __restrict__ x, u16* __restrict__ xb,
                       const float* __restrict__ wih1, const float* __restrict__ whh1, u16* __restrict__ wpk1,
                       const float* __restrict__ wih2, const float* __restrict__ whh2, u16* __restrict__ wpk2,
                       const float* __restrict__ lr1, const float* __restrict__ ll1, u16* __restrict__ epk1,
                       const float* __restrict__ lr2, const float* __restrict__ ll2, u16* __restrict__ epk2,
                       const float* __restrict__ linw, u16* __restrict__ hpk,
                       const float* __restrict__ bi1, const float* __restrict__ bh1, float* __restrict__ bs1,
                       const float* __restrict__ bi2, const float* __restrict__ bh2, float* __restrict__ bs2) {
  int b = blockIdx.x;
  if (b < 128) {
    const float* wih = (b < 64) ? wih1 : wih2;
    const float* whh = (b < 64) ? whh1 : whh2;
    u16* wpk = (b < 64) ? wpk1 : wpk2;
    int t = (b & 63) * 256 + threadIdx.x;          // 0..16383
    int lane = t & 63, kt = (t >> 6) & 7, g = (t >> 9) & 3, w = (t >> 11) & 7;
    int col = g * 128 + w * 16 + (lane & 15);
    int k0 = kt * 32 + (lane >> 4) * 8;
    float sc = (g == 2) ? 2.f * LOG2E : LOG2E;
#pragma unroll
    for (int j = 0; j < 8; ++j) {
      int k = k0 + j;
      float v = (k < 128) ? wih[col * 128 + k] : whh[col * 128 + k - 128];
      wpk[t * 8 + j] = f2bf(sc * v);
    }
  } else if (b < 160) {
    const float* lrw = (b < 144) ? lr1 : lr2;
    const float* llw = (b < 144) ? ll1 : ll2;
    u16* epk = (b < 144) ? epk1 : epk2;
    int t = ((b - 128) & 15) * 256 + threadIdx.x;  // 0..4095
    int lane = t & 63, kt = (t >> 6) & 7, w = (t >> 9) & 7;
    int col = w * 16 + (lane & 15);
    int k0 = kt * 32 + (lane >> 4) * 8;
#pragma unroll
    for (int j = 0; j < 8; ++j) {
      int k = k0 + j;
      epk[t * 8 + j] = f2bf(k < 128 ? lrw[col * 128 + k] : llw[col * 128 + k - 128]);
    }
  } else if (b < 164) {
    int t = (b - 160) * 256 + threadIdx.x;         // 0..1023
    int lane = t & 63, kt = (t >> 6) & 3, w = (t >> 8) & 3;
    int col = w * 16 + (lane & 15);
    int k0 = kt * 32 + (lane >> 4) * 8;
#pragma unroll
    for (int j = 0; j < 8; ++j) hpk[t * 8 + j] = f2bf(linw[col * 128 + k0 + j]);
  } else if (b < 168) {
    int t = (b - 164) * 256 + threadIdx.x;         // 0..1023
    if (t < 1024) {
      int i = t & 511;
      float sc = ((i >> 7) == 2) ? 2.f * LOG2E : LOG2E;
      if (t < 512) bs1[i] = sc * (bi1[i] + bh1[i]);
      else bs2[i] = sc * (bi2[i] + bh2[i]);
    }
  } else {
    int i = (b - 168) * 256 + threadIdx.x;
    int stride = (gridDim.x - 168) * 256;
    for (; i < NN * 128 / 4; i += stride) {
      float4 v = ((const float4*)x)[i];
      ushort4 o;
      o.x = f2bf(v.x); o.y = f2bf(v.y); o.z = f2bf(v.z); o.w = f2bf(v.w);
      ((ushort4*)xb)[i] = o;
    }
  }
}

// ---------------------------------------------------------------------------
// Fused SAGE-LSTM layer, v12: DUAL-STREAM. 512 thr = 8 waves, MT=32 = two
// independent 16-node LSTM streams (A: rows 0-15, B: rows 16-31) sharing the
// register-resident weight panel (wreg 128 VGPR, loaded once).
// Superstep order  hA -> hB -> EW_A -> xA(s+1) -> ldA(s+2) -> EW_B ->
// xB(s+1) -> ldB(s+2) -> EBAR  interleaves stream A's trans-chain with
// stream B's MFMAs (and vice versa) WITHIN each wave: both pipes stay fed
// without extra occupancy; barriers per node-step halve.
// x A-fragments per-lane direct from global (L1-served, v10); AH per stream
// double-buffered, XOR-swizzle byte ^= (row&15)<<4. EW math identical to
// v10 (bit-identical output).
// ---------------------------------------------------------------------------

#define XLOADS(XF, DCODE, ROFF)                                               \
  do {                                                                        \
    int idx_;                                                                 \
    if ((DCODE) < DEG) idx_ = IDXT[(DCODE) * 32 + (ROFF) + lr];               \
    else { idx_ = node0 + (ROFF) + lr; if (idx_ >= NN) idx_ = NN - 1; }       \
    const u16* b_ = xin + (size_t)idx_ * 128 + lh * 8;                        \
    XF[0] = *(const bf16x8*)(b_);                                             \
    XF[1] = *(const bf16x8*)(b_ + 32);                                        \
    XF[2] = *(const bf16x8*)(b_ + 64);                                        \
    XF[3] = *(const bf16x8*)(b_ + 96);                                        \
  } while (0)

#define XPARTS(ACC, XF)                                                       \
  do {                                                                        \
    __builtin_amdgcn_s_setprio(1);                                            \
    _Pragma("unroll") for (int g = 0; g < 4; ++g)                             \
        ACC[g] = (f32x4){gb[g], gb[g], gb[g], gb[g]};                         \
    _Pragma("unroll") for (int kt = 0; kt < 4; ++kt)                          \
        _Pragma("unroll") for (int g = 0; g < 4; ++g)                         \
            ACC[g] = __builtin_amdgcn_mfma_f32_16x16x32_bf16(XF[kt], wreg[g][kt], ACC[g], 0, 0, 0); \
    __builtin_amdgcn_s_setprio(0);                                            \
  } while (0)

#define HPARTS(ACC, AHSRC)                                                    \
  do {                                                                        \
    _Pragma("unroll") for (int kt = 0; kt < 4; ++kt) {                        \
      bf16x8 af = *(const bf16x8*)((const char*)(AHSRC) + lr * 256 +          \
                                   ((kt * 64 + lh * 16) ^ ((lr & 15) << 4))); \
      _Pragma("unroll") for (int g = 0; g < 4; ++g)                           \
        ACC[g] = __builtin_amdgcn_mfma_f32_16x16x32_bf16(af, wreg[g][4 + kt], ACC[g], 0, 0, 0); \
    }                                                                         \
  } while (0)

#define EWS(ACC, C4, AHDST)                                                   \
  do {                                                                        \
    _Pragma("unroll") for (int r = 0; r < 4; ++r) {                           \
      float iv = rcp_(1.f + ex2_(-ACC[0][r]));                                \
      float fv = rcp_(1.f + ex2_(-ACC[1][r]));                                \
      float gv = 1.f - 2.f * rcp_(1.f + ex2_(ACC[2][r]));                     \
      float ov = rcp_(1.f + ex2_(-ACC[3][r]));                                \
      float cv = fv * C4[r] + iv * gv;                                        \
      C4[r] = cv;                                                             \
      float th = 1.f - 2.f * rcp_(1.f + ex2_(2.f * LOG2E * cv));              \
      int row = lh * 4 + r;                                                   \
      int jj = 2 * (w * 16 + lr);                                             \
      *(u16*)((char*)(AHDST) + row * 256 + (jj ^ ((row & 15) << 4))) =        \
          f2bf(ov * th);                                                      \
    }                                                                         \
  } while (0)

#define EBAR()                                                                \
  do {                                                                        \
    asm volatile("s_waitcnt lgkmcnt(0)" ::: "memory");                        \
    __builtin_amdgcn_s_barrier();                                             \
    __builtin_amdgcn_sched_barrier(0);                                        \
  } while (0)

template <int L2>
__global__ __launch_bounds__(512, 2) void k_layer(
    const u16* __restrict__ xin, const int* __restrict__ src,
    const u16* __restrict__ wpk, const float* __restrict__ bsum,
    const u16* __restrict__ epk, const float* __restrict__ linlb,
    u16* __restrict__ hout, const u16* __restrict__ hpk,
    const float* __restrict__ linb, float* __restrict__ dout) {
  __shared__ __align__(16) u16 AHA[2][16 * 128];  // stream A h, 2 x 4 KB
  __shared__ __align__(16) u16 AHB[2][16 * 128];  // stream B h, 2 x 4 KB
  __shared__ int IDXT[DEG * MT];                  // transposed [d][r], 2 KB

  const int tid = threadIdx.x;
  const int w = tid >> 6, l = tid & 63;
  const int lr = l & 15, lh = l >> 4;
  const int node0 = blockIdx.x * MT;

  // ---- register-resident weight panel: 32 frags = 128 VGPRs, loaded ONCE ----
  bf16x8 wreg[4][8];
#pragma unroll
  for (int g = 0; g < 4; ++g)
#pragma unroll
    for (int kt = 0; kt < 8; ++kt)
      wreg[g][kt] = *(const bf16x8*)(wpk + (size_t)(((w * 4 + g) * 8 + kt) * 64 + l) * 8);

  // transposed neighbor indices: IDXT[d*32 + r] = src[(node0+r)*DEG + d]
  {
    int node = node0 + (tid >> 4);
    IDXT[(tid & 15) * 32 + (tid >> 4)] = (node < NN) ? src[node * DEG + (tid & 15)] : 0;
  }

  float gb[4];
#pragma unroll
  for (int g = 0; g < 4; ++g) gb[g] = bsum[g * 128 + w * 16 + lr];
  float eb = linlb[w * 16 + lr];
  __syncthreads();  // IDXT ready

  bf16x8 xfA[4], xfB[4];
  f32x4 accA[4], accB[4];
  f32x4 cA = (f32x4){0.f, 0.f, 0.f, 0.f};
  f32x4 cB = (f32x4){0.f, 0.f, 0.f, 0.f};

  // prologue: x(0) frags + x-part(0) for both streams; prefetch x(1)
  XLOADS(xfA, 0, 0);
  XLOADS(xfB, 0, 16);
  XPARTS(accA, xfA);
  XPARTS(accB, xfB);
  XLOADS(xfA, 1, 0);
  XLOADS(xfB, 1, 16);

#pragma unroll 1
  for (int step = 0; step < DEG; ++step) {
    const int cb = step & 1, nb = cb ^ 1;

    // h-parts first (MFMA pipe); EW_A's trans then overlaps hB's in-flight
    if (step) {
      __builtin_amdgcn_s_setprio(1);
      HPARTS(accA, AHA[cb]);
      HPARTS(accB, AHB[cb]);
      __builtin_amdgcn_s_setprio(0);
    }

    EWS(accA, cA, AHA[nb]);          // trans(A)  || tail of hB MFMAs
    if (step < DEG - 1) {
      XPARTS(accA, xfA);             // MFMA(A,s+1)
      XLOADS(xfA, step + 2, 0);      // VMEM(A,s+2)
    }
    EWS(accB, cB, AHB[nb]);          // trans(B)  || xA MFMAs executing
    if (step < DEG - 1) {
      XPARTS(accB, xfB);             // MFMA(B,s+1)
      XLOADS(xfB, step + 2, 16);     // VMEM(B,s+2)
    }

    EBAR();  // lgkmcnt(0)+barrier: AH handoff; xf global loads stay in flight
  }

  // Epilogue: out = lin_r(x_own) + lin_l(h_final) + b, ReLU.
  // xfA/xfB hold own-x frags (d=16, loaded at step 14); AH*[0] final h.
  f32x4 eaccA = (f32x4){eb, eb, eb, eb};
  f32x4 eaccB = (f32x4){eb, eb, eb, eb};
#pragma unroll
  for (int kt = 0; kt < 4; ++kt) {
    bf16x8 bf = *(const bf16x8*)(epk + (size_t)((w * 8 + kt) * 64 + l) * 8);
    eaccA = __builtin_amdgcn_mfma_f32_16x16x32_bf16(xfA[kt], bf, eaccA, 0, 0, 0);
    eaccB = __builtin_amdgcn_mfma_f32_16x16x32_bf16(xfB[kt], bf, eaccB, 0, 0, 0);
  }
#pragma unroll
  for (int kt = 0; kt < 4; ++kt) {
    int ofs = (kt * 64 + lh * 16) ^ ((lr & 15) << 4);
    bf16x8 afA = *(const bf16x8*)((const char*)AHA[0] + lr * 256 + ofs);
    bf16x8 afB = *(const bf16x8*)((const char*)AHB[0] + lr * 256 + ofs);
    bf16x8 bf = *(const bf16x8*)(epk + (size_t)((w * 8 + 4 + kt) * 64 + l) * 8);
    eaccA = __builtin_amdgcn_mfma_f32_16x16x32_bf16(afA, bf, eaccA, 0, 0, 0);
    eaccB = __builtin_amdgcn_mfma_f32_16x16x32_bf16(afB, bf, eaccB, 0, 0, 0);
  }

  if constexpr (!L2) {
#pragma unroll
    for (int r = 0; r < 4; ++r) {
      int nodeA = node0 + lh * 4 + r;
      int nodeB = node0 + 16 + lh * 4 + r;
      if (nodeA < NN)
        hout[(size_t)nodeA * 128 + w * 16 + lr] = f2bf(fmaxf(eaccA[r], 0.f));
      if (nodeB < NN)
        hout[(size_t)nodeB * 128 + w * 16 + lr] = f2bf(fmaxf(eaccB[r], 0.f));
    }
  } else {
    // stash relu(h2): A -> AHA[1], B -> AHB[1]; then parallel heads
#pragma unroll
    for (int r = 0; r < 4; ++r) {
      int row = lh * 4 + r;
      int jj = 2 * (w * 16 + lr);
      *(u16*)((char*)AHA[1] + row * 256 + (jj ^ ((row & 15) << 4))) =
          f2bf(fmaxf(eaccA[r], 0.f));
      *(u16*)((char*)AHB[1] + row * 256 + (jj ^ ((row & 15) << 4))) =
          f2bf(fmaxf(eaccB[r], 0.f));
    }
    __syncthreads();
    {
      // waves 0-3: head of stream A; waves 4-7: head of stream B
      const u16* stash = (w < 4) ? AHB[1] : AHA[1];
      stash = (w < 4) ? AHA[1] : AHB[1];
      int w0 = w & 3;
      int roff = (w < 4) ? 0 : 16;
      float hb = linb[w0 * 16 + lr];
      f32x4 hacc = (f32x4){hb, hb, hb, hb};
#pragma unroll
      for (int kt = 0; kt < 4; ++kt) {
        bf16x8 af = *(const bf16x8*)((const char*)stash + lr * 256 +
                                     ((kt * 64 + lh * 16) ^ ((lr & 15) << 4)));
        bf16x8 bf = *(const bf16x8*)(hpk + (size_t)((w0 * 4 + kt) * 64 + l) * 8);
        hacc = __builtin_amdgcn_mfma_f32_16x16x32_bf16(af, bf, hacc, 0, 0, 0);
      }
#pragma unroll
      for (int r = 0; r < 4; ++r) {
        int node = node0 + roff + lh * 4 + r;
        if (node < NN) dout[(size_t)node * 64 + w0 * 16 + lr] = hacc[r];
      }
    }
  }
}

extern "C" void kernel_launch(void* const* d_in, const int* in_sizes, int n_in,
                              void* d_out, int out_size, void* d_ws, size_t ws_size,
                              hipStream_t stream) {
  const float* x    = (const float*)d_in[0];
  const int*   edge = (const int*)d_in[1];   // src = first N*DEG entries
  const float* wih1 = (const float*)d_in[2];
  const float* whh1 = (const float*)d_in[3];
  const float* bih1 = (const float*)d_in[4];
  const float* bhh1 = (const float*)d_in[5];
  const float* ll1w = (const float*)d_in[6];
  const float* ll1b = (const float*)d_in[7];
  const float* lr1w = (const float*)d_in[8];
  const float* wih2 = (const float*)d_in[9];
  const float* whh2 = (const float*)d_in[10];
  const float* bih2 = (const float*)d_in[11];
  const float* bhh2 = (const float*)d_in[12];
  const float* ll2w = (const float*)d_in[13];
  const float* ll2b = (const float*)d_in[14];
  const float* lr2w = (const float*)d_in[15];
  const float* linw = (const float*)d_in[16];
  const float* linb = (const float*)d_in[17];

  char* ws = (char*)d_ws;
  u16* xb    = (u16*)(ws);                       // 12,800,000 B
  u16* h1b   = (u16*)(ws + 12800000);            // 12,800,000 B
  u16* wpk1  = (u16*)(ws + 25600000);            //    262,144 B
  u16* wpk2  = (u16*)(ws + 25862144);            //    262,144 B
  u16* epk1  = (u16*)(ws + 26124288);            //     65,536 B
  u16* epk2  = (u16*)(ws + 26189824);            //     65,536 B
  u16* hpk   = (u16*)(ws + 26255360);            //     16,384 B
  float* bs1 = (float*)(ws + 26271744);          //      2,048 B
  float* bs2 = (float*)(ws + 26273792);          //      2,048 B

  k_prep<<<1000, 256, 0, stream>>>(x, xb,
                                   wih1, whh1, wpk1, wih2, whh2, wpk2,
                                   lr1w, ll1w, epk1, lr2w, ll2w, epk2,
                                   linw, hpk,
                                   bih1, bhh1, bs1, bih2, bhh2, bs2);
  k_layer<0><<<NBLK, 512, 0, stream>>>(xb, edge, wpk1, bs1, epk1, ll1b,
                                       h1b, nullptr, nullptr, nullptr);
  k_layer<1><<<NBLK, 512, 0, stream>>>(h1b, edge, wpk2, bs2, epk2, ll2b,
                                       nullptr, hpk, linb, (float*)d_out);
}

// Round 13
// 497.871 us; speedup vs baseline: 1.3735x; 1.3029x over previous
//
#include <hip/hip_runtime.h>
#include <stdint.h>

#define NN 50000
#define DEG 16
#define MT 32
#define NBLK ((NN + MT - 1) / MT)
#define LOG2E 1.4426950408889634f

typedef short bf16x8 __attribute__((ext_vector_type(8)));
typedef float f32x4 __attribute__((ext_vector_type(4)));
typedef unsigned short u16;
typedef unsigned int u32;

static __device__ __forceinline__ u16 f2bf(float f) {
  union { float f; u32 u; } v; v.f = f;
  u32 u = v.u + 0x7FFFu + ((v.u >> 16) & 1u);   // round-to-nearest-even
  return (u16)(u >> 16);
}
// hardware packed f32->bf16 (RNE) — bit-identical to f2bf, 1 op for 2 values
static __device__ __forceinline__ u32 cvtpk(float lo, float hi) {
  u32 r;
  asm("v_cvt_pk_bf16_f32 %0, %1, %2" : "=v"(r) : "v"(lo), "v"(hi));
  return r;
}
static __device__ __forceinline__ float rcp_(float x) {
  return __builtin_amdgcn_rcpf(x);
}
static __device__ __forceinline__ float ex2_(float x) {
  return __builtin_amdgcn_exp2f(x);
}
static __device__ __forceinline__ void gload_lds16(const void* g, void* l) {
  __builtin_amdgcn_global_load_lds(
      (const __attribute__((address_space(1))) void*)g,
      (__attribute__((address_space(3))) void*)l, 16, 0, 0);
}

// ---------------------------------------------------------------------------
// Prep (v7 layout): bf16-convert x, prepack MFMA B-fragments, bias sums.
// Gate weights/biases PRE-SCALED by log2e (i,f,o) / 2*log2e (g).
//   wpk[(((w*4+g)*8+kt)*64+lane)*8+j] = sc * W[col][k],
//   col = g*128 + w*16 + (lane&15),  k = kt*32 + (lane>>4)*8 + j,
//   W = [w_ih | w_hh] along K  (kt 0..3 = x-part, kt 4..7 = h-part).
// ---------------------------------------------------------------------------
__global__ void k_prep(const float* __restrict__ x, u16* __restrict__ xb,
                       const float* __restrict__ wih1, const float* __restrict__ whh1, u16* __restrict__ wpk1,
                       const float* __restrict__ wih2, const float* __restrict__ whh2, u16* __restrict__ wpk2,
                       const float* __restrict__ lr1, const float* __restrict__ ll1, u16* __restrict__ epk1,
                       const float* __restrict__ lr2, const float* __restrict__ ll2, u16* __restrict__ epk2,
                       const float* __restrict__ linw, u16* __restrict__ hpk,
                       const float* __restrict__ bi1, const float* __restrict__ bh1, float* __restrict__ bs1,
                       const float* __restrict__ bi2, const float* __restrict__ bh2, float* __restrict__ bs2) {
  int b = blockIdx.x;
  if (b < 128) {
    const float* wih = (b < 64) ? wih1 : wih2;
    const float* whh = (b < 64) ? whh1 : whh2;
    u16* wpk = (b < 64) ? wpk1 : wpk2;
    int t = (b & 63) * 256 + threadIdx.x;          // 0..16383
    int lane = t & 63, kt = (t >> 6) & 7, g = (t >> 9) & 3, w = (t >> 11) & 7;
    int col = g * 128 + w * 16 + (lane & 15);
    int k0 = kt * 32 + (lane >> 4) * 8;
    float sc = (g == 2) ? 2.f * LOG2E : LOG2E;
#pragma unroll
    for (int j = 0; j < 8; ++j) {
      int k = k0 + j;
      float v = (k < 128) ? wih[col * 128 + k] : whh[col * 128 + k - 128];
      wpk[t * 8 + j] = f2bf(sc * v);
    }
  } else if (b < 160) {
    const float* lrw = (b < 144) ? lr1 : lr2;
    const float* llw = (b < 144) ? ll1 : ll2;
    u16* epk = (b < 144) ? epk1 : epk2;
    int t = ((b - 128) & 15) * 256 + threadIdx.x;  // 0..4095
    int lane = t & 63, kt = (t >> 6) & 7, w = (t >> 9) & 7;
    int col = w * 16 + (lane & 15);
    int k0 = kt * 32 + (lane >> 4) * 8;
#pragma unroll
    for (int j = 0; j < 8; ++j) {
      int k = k0 + j;
      epk[t * 8 + j] = f2bf(k < 128 ? lrw[col * 128 + k] : llw[col * 128 + k - 128]);
    }
  } else if (b < 164) {
    int t = (b - 160) * 256 + threadIdx.x;         // 0..1023
    int lane = t & 63, kt = (t >> 6) & 3, w = (t >> 8) & 3;
    int col = w * 16 + (lane & 15);
    int k0 = kt * 32 + (lane >> 4) * 8;
#pragma unroll
    for (int j = 0; j < 8; ++j) hpk[t * 8 + j] = f2bf(linw[col * 128 + k0 + j]);
  } else if (b < 168) {
    int t = (b - 164) * 256 + threadIdx.x;         // 0..1023
    if (t < 1024) {
      int i = t & 511;
      float sc = ((i >> 7) == 2) ? 2.f * LOG2E : LOG2E;
      if (t < 512) bs1[i] = sc * (bi1[i] + bh1[i]);
      else bs2[i] = sc * (bi2[i] + bh2[i]);
    }
  } else {
    int i = (b - 168) * 256 + threadIdx.x;
    int stride = (gridDim.x - 168) * 256;
    for (; i < NN * 128 / 4; i += stride) {
      float4 v = ((const float4*)x)[i];
      ushort4 o;
      o.x = f2bf(v.x); o.y = f2bf(v.y); o.z = f2bf(v.z); o.w = f2bf(v.w);
      ((ushort4*)xb)[i] = o;
    }
  }
}

// ---------------------------------------------------------------------------
// Fused SAGE-LSTM layer, v13 = v7 (best: 298us/layer) + two micro-opts:
//  * h-write conversions via v_cvt_pk_bf16_f32 (HW RNE, bit-identical to the
//    manual f2bf): 8 conversions/lane-step drop from ~40 VALU ops to ~8.
//  * s_setprio(1) around MFMA clusters (T5).
// Structure frozen from v7: 512 thr = 8 waves, MT=32, register-resident
// weight panel (128 VGPR), triple-buffered AX gather via global_load_lds,
// counted-vmcnt barrier CBAR(1) (2-ahead gather), AH double-buffered,
// LDS XOR-swizzle byte ^= (row&15)<<4.
// ---------------------------------------------------------------------------

#define GATHER(DCODE, PDST)                                                   \
  do {                                                                        \
    int idx_;                                                                 \
    if ((DCODE) < DEG) idx_ = IDX[grow * DEG + (DCODE)];                      \
    else idx_ = (node0 + grow < NN) ? node0 + grow : NN - 1;                  \
    const char* gsw_ = (const char*)(xin + (size_t)idx_ * 128) +              \
                       ((lr * 16) ^ ((grow & 15) << 4));                      \
    gload_lds16(gsw_, (PDST) + (w * 4) * 128);                                \
  } while (0)

#define CBAR(N)                                                               \
  do {                                                                        \
    asm volatile("s_waitcnt vmcnt(" #N ") lgkmcnt(0)" ::: "memory");          \
    __builtin_amdgcn_s_barrier();                                             \
    __builtin_amdgcn_sched_barrier(0);                                        \
  } while (0)

template <int L2>
__global__ __launch_bounds__(512, 2) void k_layer(
    const u16* __restrict__ xin, const int* __restrict__ src,
    const u16* __restrict__ wpk, const float* __restrict__ bsum,
    const u16* __restrict__ epk, const float* __restrict__ linlb,
    u16* __restrict__ hout, const u16* __restrict__ hpk,
    const float* __restrict__ linb, float* __restrict__ dout) {
  __shared__ __align__(16) u16 AX[3][MT * 128];   // 3 x 8 KB (triple buffer)
  __shared__ __align__(16) u16 AH[2][MT * 128];   // 2 x 8 KB
  __shared__ int IDX[MT * DEG];                   // 2 KB

  const int tid = threadIdx.x;
  const int w = tid >> 6, l = tid & 63;
  const int lr = l & 15, lh = l >> 4;
  const int node0 = blockIdx.x * MT;
  const int grow = w * 4 + lh;  // this lane's gather row

  // ---- register-resident weight panel: 32 frags = 128 VGPRs, loaded ONCE ----
  bf16x8 wreg[4][8];
#pragma unroll
  for (int g = 0; g < 4; ++g)
#pragma unroll
    for (int kt = 0; kt < 8; ++kt)
      wreg[g][kt] = *(const bf16x8*)(wpk + (size_t)(((w * 4 + g) * 8 + kt) * 64 + l) * 8);

  IDX[tid] = (node0 + (tid >> 4) < NN) ? src[node0 * DEG + tid] : 0;

  float gb[4];
#pragma unroll
  for (int g = 0; g < 4; ++g) gb[g] = bsum[g * 128 + w * 16 + lr];
  float eb = linlb[w * 16 + lr];
  __syncthreads();  // IDX ready; vmcnt fully drained (baseline 0 outstanding)

  // prologue: gather x_0 -> AX[0], x_1 -> AX[1] (2 outstanding)
  GATHER(0, AX[0]);
  GATHER(1, AX[1]);

  f32x4 c[2];
  c[0] = (f32x4){0.f, 0.f, 0.f, 0.f};
  c[1] = (f32x4){0.f, 0.f, 0.f, 0.f};
  CBAR(1);  // x_0 landed; x_1 still in flight

  u16 *pA = AX[0], *pB = AX[1], *pC = AX[2];

#pragma unroll 1
  for (int step = 0; step < DEG; ++step) {
    const int cb = step & 1, nb = cb ^ 1;

    // issue gather(step+2) into the free buffer (d=16 -> own features)
    if (step < DEG - 1) GATHER(step + 2, pC);

    // acc init = gate bias (pre-scaled): free bias add via MFMA C-in
    f32x4 acc[2][4];
#pragma unroll
    for (int mt = 0; mt < 2; ++mt)
#pragma unroll
      for (int g = 0; g < 4; ++g)
        acc[mt][g] = (f32x4){gb[g], gb[g], gb[g], gb[g]};

    // x-part of gates: K tiles 0..3 (A from AX[pA], B from registers)
    __builtin_amdgcn_s_setprio(1);
#pragma unroll
    for (int kt = 0; kt < 4; ++kt) {
      bf16x8 af[2];
#pragma unroll
      for (int mt = 0; mt < 2; ++mt) {
        int row = mt * 16 + lr;
        af[mt] = *(const bf16x8*)((const char*)pA + row * 256 +
                                  ((kt * 64 + lh * 16) ^ ((row & 15) << 4)));
      }
#pragma unroll
      for (int g = 0; g < 4; ++g)
#pragma unroll
        for (int mt = 0; mt < 2; ++mt)
          acc[mt][g] = __builtin_amdgcn_mfma_f32_16x16x32_bf16(af[mt], wreg[g][kt], acc[mt][g], 0, 0, 0);
    }

    // h-part of gates: K tiles 4..7 (h == 0 at step 0)
    if (step) {
#pragma unroll
      for (int kt = 0; kt < 4; ++kt) {
        bf16x8 af[2];
#pragma unroll
        for (int mt = 0; mt < 2; ++mt) {
          int row = mt * 16 + lr;
          af[mt] = *(const bf16x8*)((const char*)AH[cb] + row * 256 +
                                    ((kt * 64 + lh * 16) ^ ((row & 15) << 4)));
        }
#pragma unroll
        for (int g = 0; g < 4; ++g)
#pragma unroll
          for (int mt = 0; mt < 2; ++mt)
            acc[mt][g] = __builtin_amdgcn_mfma_f32_16x16x32_bf16(af[mt], wreg[g][4 + kt], acc[mt][g], 0, 0, 0);
      }
    }
    __builtin_amdgcn_s_setprio(0);

    // LSTM elementwise (exp2 domain); write new h (bf16) into AH[nb].
    // Conversions via packed HW cvt (RNE, bit-identical), 2 values per op.
#pragma unroll
    for (int mt = 0; mt < 2; ++mt) {
      float hv[4];
#pragma unroll
      for (int r = 0; r < 4; ++r) {
        float iv = rcp_(1.f + ex2_(-acc[mt][0][r]));
        float fv = rcp_(1.f + ex2_(-acc[mt][1][r]));
        float gv = 1.f - 2.f * rcp_(1.f + ex2_(acc[mt][2][r]));
        float ov = rcp_(1.f + ex2_(-acc[mt][3][r]));
        float cv = fv * c[mt][r] + iv * gv;
        c[mt][r] = cv;
        float th = 1.f - 2.f * rcp_(1.f + ex2_(2.f * LOG2E * cv));
        hv[r] = ov * th;
      }
      u32 pk01 = cvtpk(hv[0], hv[1]);
      u32 pk23 = cvtpk(hv[2], hv[3]);
      const int jj = 2 * (w * 16 + lr);
#pragma unroll
      for (int r = 0; r < 4; ++r) {
        int row = mt * 16 + lh * 4 + r;
        u16 hb16 = (r == 0) ? (u16)pk01 : (r == 1) ? (u16)(pk01 >> 16)
                   : (r == 2) ? (u16)pk23 : (u16)(pk23 >> 16);
        *(u16*)((char*)AH[nb] + row * 256 + (jj ^ ((row & 15) << 4))) = hb16;
      }
    }

    // counted barrier: drain gather(step+1) only; keep gather(step+2) flying
    if (step < DEG - 1) CBAR(1);
    else CBAR(0);  // last step: drain the own-x gather for the epilogue

    u16* t_ = pA; pA = pB; pB = t_;
    t_ = pB; pB = pC; pC = t_;  // rotate: pA<-pB, pB<-pC, pC<-old pA
  }

  // Epilogue: out = lin_r(x_own) + lin_l(h_final) + b, ReLU.
  // After 16 rotations pA holds the d=16 buffer (own x); AH[0] the final h.
  f32x4 eacc[2];
  eacc[0] = (f32x4){eb, eb, eb, eb};
  eacc[1] = (f32x4){eb, eb, eb, eb};
#pragma unroll
  for (int kt = 0; kt < 8; ++kt) {
    const u16* srcb = (kt < 4) ? pA : AH[0];
    int kb = (kt & 3) * 64 + lh * 16;
    bf16x8 af[2];
#pragma unroll
    for (int mt = 0; mt < 2; ++mt) {
      int row = mt * 16 + lr;
      af[mt] = *(const bf16x8*)((const char*)srcb + row * 256 +
                                (kb ^ ((row & 15) << 4)));
    }
    bf16x8 bf = *(const bf16x8*)(epk + (size_t)((w * 8 + kt) * 64 + l) * 8);
#pragma unroll
    for (int mt = 0; mt < 2; ++mt)
      eacc[mt] = __builtin_amdgcn_mfma_f32_16x16x32_bf16(af[mt], bf, eacc[mt], 0, 0, 0);
  }

  if constexpr (!L2) {
#pragma unroll
    for (int mt = 0; mt < 2; ++mt) {
      u32 pk01 = cvtpk(fmaxf(eacc[mt][0], 0.f), fmaxf(eacc[mt][1], 0.f));
      u32 pk23 = cvtpk(fmaxf(eacc[mt][2], 0.f), fmaxf(eacc[mt][3], 0.f));
#pragma unroll
      for (int r = 0; r < 4; ++r) {
        int node = node0 + mt * 16 + lh * 4 + r;
        if (node < NN) {
          u16 hb16 = (r == 0) ? (u16)pk01 : (r == 1) ? (u16)(pk01 >> 16)
                     : (r == 2) ? (u16)pk23 : (u16)(pk23 >> 16);
          hout[(size_t)node * 128 + w * 16 + lr] = hb16;
        }
      }
    }
  } else {
    // stash relu(h2) into AH[1] (free), then fused 128->64 head (waves 0..3)
#pragma unroll
    for (int mt = 0; mt < 2; ++mt) {
      u32 pk01 = cvtpk(fmaxf(eacc[mt][0], 0.f), fmaxf(eacc[mt][1], 0.f));
      u32 pk23 = cvtpk(fmaxf(eacc[mt][2], 0.f), fmaxf(eacc[mt][3], 0.f));
      const int jj = 2 * (w * 16 + lr);
#pragma unroll
      for (int r = 0; r < 4; ++r) {
        int row = mt * 16 + lh * 4 + r;
        u16 hb16 = (r == 0) ? (u16)pk01 : (r == 1) ? (u16)(pk01 >> 16)
                   : (r == 2) ? (u16)pk23 : (u16)(pk23 >> 16);
        *(u16*)((char*)AH[1] + row * 256 + (jj ^ ((row & 15) << 4))) = hb16;
      }
    }
    __syncthreads();
    if (w < 4) {
      float hb = linb[w * 16 + lr];
      f32x4 hacc[2];
      hacc[0] = (f32x4){hb, hb, hb, hb};
      hacc[1] = (f32x4){hb, hb, hb, hb};
#pragma unroll
      for (int kt = 0; kt < 4; ++kt) {
        bf16x8 af[2];
#pragma unroll
        for (int mt = 0; mt < 2; ++mt) {
          int row = mt * 16 + lr;
          af[mt] = *(const bf16x8*)((const char*)AH[1] + row * 256 +
                                    ((kt * 64 + lh * 16) ^ ((row & 15) << 4)));
        }
        bf16x8 bf = *(const bf16x8*)(hpk + (size_t)((w * 4 + kt) * 64 + l) * 8);
#pragma unroll
        for (int mt = 0; mt < 2; ++mt)
          hacc[mt] = __builtin_amdgcn_mfma_f32_16x16x32_bf16(af[mt], bf, hacc[mt], 0, 0, 0);
      }
#pragma unroll
      for (int mt = 0; mt < 2; ++mt)
#pragma unroll
        for (int r = 0; r < 4; ++r) {
          int node = node0 + mt * 16 + lh * 4 + r;
          if (node < NN) dout[(size_t)node * 64 + w * 16 + lr] = hacc[mt][r];
        }
    }
  }
}

extern "C" void kernel_launch(void* const* d_in, const int* in_sizes, int n_in,
                              void* d_out, int out_size, void* d_ws, size_t ws_size,
                              hipStream_t stream) {
  const float* x    = (const float*)d_in[0];
  const int*   edge = (const int*)d_in[1];   // src = first N*DEG entries
  const float* wih1 = (const float*)d_in[2];
  const float* whh1 = (const float*)d_in[3];
  const float* bih1 = (const float*)d_in[4];
  const float* bhh1 = (const float*)d_in[5];
  const float* ll1w = (const float*)d_in[6];
  const float* ll1b = (const float*)d_in[7];
  const float* lr1w = (const float*)d_in[8];
  const float* wih2 = (const float*)d_in[9];
  const float* whh2 = (const float*)d_in[10];
  const float* bih2 = (const float*)d_in[11];
  const float* bhh2 = (const float*)d_in[12];
  const float* ll2w = (const float*)d_in[13];
  const float* ll2b = (const float*)d_in[14];
  const float* lr2w = (const float*)d_in[15];
  const float* linw = (const float*)d_in[16];
  const float* linb = (const float*)d_in[17];

  char* ws = (char*)d_ws;
  u16* xb    = (u16*)(ws);                       // 12,800,000 B
  u16* h1b   = (u16*)(ws + 12800000);            // 12,800,000 B
  u16* wpk1  = (u16*)(ws + 25600000);            //    262,144 B
  u16* wpk2  = (u16*)(ws + 25862144);            //    262,144 B
  u16* epk1  = (u16*)(ws + 26124288);            //     65,536 B
  u16* epk2  = (u16*)(ws + 26189824);            //     65,536 B
  u16* hpk   = (u16*)(ws + 26255360);            //     16,384 B
  float* bs1 = (float*)(ws + 26271744);          //      2,048 B
  float* bs2 = (float*)(ws + 26273792);          //      2,048 B

  k_prep<<<1000, 256, 0, stream>>>(x, xb,
                                   wih1, whh1, wpk1, wih2, whh2, wpk2,
                                   lr1w, ll1w, epk1, lr2w, ll2w, epk2,
                                   linw, hpk,
                                   bih1, bhh1, bs1, bih2, bhh2, bs2);
  k_layer<0><<<NBLK, 512, 0, stream>>>(xb, edge, wpk1, bs1, epk1, ll1b,
                                       h1b, nullptr, nullptr, nullptr);
  k_layer<1><<<NBLK, 512, 0, stream>>>(h1b, edge, wpk2, bs2, epk2, ll2b,
                                       nullptr, hpk, linb, (float*)d_out);
}